// Round 1
// baseline (8075.343 us; speedup 1.0000x reference)
//
#include <hip/hip_runtime.h>

// Problem dims
constexpr int B = 128, Cin = 64, H = 56, W = 56;
constexpr int Cout = 128, Ho = 28, Wo = 28;
constexpr int HW = Ho * Wo;              // 784
constexpr int NOUT = B * Cout * HW;      // 12,845,056
constexpr float EPS_ = 1e-5f;
constexpr int NSLICE = 16;               // n-slices per channel for stats partials
constexpr int NPART = Cout * NSLICE * 2; // floats per stats partial buffer

// ---------------- block reduction helper (256 threads = 4 waves) ----------------
__device__ inline void block_reduce2(float& s, float& s2) {
    #pragma unroll
    for (int off = 32; off > 0; off >>= 1) {
        s  += __shfl_down(s, off);
        s2 += __shfl_down(s2, off);
    }
    __shared__ float ls[4], ls2[4];
    int wid = threadIdx.x >> 6, lane = threadIdx.x & 63;
    if (lane == 0) { ls[wid] = s; ls2[wid] = s2; }
    __syncthreads();
    if (threadIdx.x == 0) {
        s  = ls[0] + ls[1] + ls[2] + ls[3];
        s2 = ls2[0] + ls2[1] + ls2[2] + ls2[3];
    }
}

// ---------------- conv1 (3x3 s2 SAME: pad_lo=0, pad_hi=1) fused with 1x1 s2 downsample ----------------
__global__ __launch_bounds__(256) void k_conv1d(
        const float* __restrict__ x, const float* __restrict__ w1,
        const float* __restrict__ wd, float* __restrict__ y1, float* __restrict__ yd) {
    int idx = blockIdx.x * 256 + threadIdx.x;
    int ow = idx % Wo; int t = idx / Wo;
    int oh = t % Ho;  t /= Ho;
    int co = t % Cout; int n = t / Cout;
    const float* wb  = w1 + co * Cin * 9;
    const float* wdb = wd + co * Cin;
    const int ih0 = oh * 2, iw0 = ow * 2;
    float acc = 0.f, accd = 0.f;
    for (int ci = 0; ci < Cin; ++ci) {
        const float* xb = x + ((size_t)n * Cin + ci) * H * W;
        const float* wc = wb + ci * 9;
        accd = fmaf(xb[ih0 * W + iw0], wdb[ci], accd);
        #pragma unroll
        for (int kh = 0; kh < 3; ++kh) {
            int ih = ih0 + kh;
            if (ih >= H) break;          // only upper-bound clip (pad_lo = 0)
            const float* xr = xb + ih * W;
            #pragma unroll
            for (int kw = 0; kw < 3; ++kw) {
                int iw = iw0 + kw;
                if (iw >= W) break;
                acc = fmaf(xr[iw], wc[kh * 3 + kw], acc);
            }
        }
    }
    y1[idx] = acc;
    yd[idx] = accd;
}

// ---------------- conv2 (3x3 s1 SAME: pad 1 both sides), input already BN+ReLU'd ----------------
__global__ __launch_bounds__(256) void k_conv2(
        const float* __restrict__ yin, const float* __restrict__ w2, float* __restrict__ y2) {
    int idx = blockIdx.x * 256 + threadIdx.x;
    int ow = idx % Wo; int t = idx / Wo;
    int oh = t % Ho;  t /= Ho;
    int co = t % Cout; int n = t / Cout;
    const float* wb = w2 + co * Cout * 9;
    float acc = 0.f;
    for (int ci = 0; ci < Cout; ++ci) {
        const float* yb = yin + ((size_t)n * Cout + ci) * HW;
        const float* wc = wb + ci * 9;
        #pragma unroll
        for (int kh = 0; kh < 3; ++kh) {
            int ih = oh + kh - 1;
            if (ih < 0 || ih >= Ho) continue;
            const float* yr = yb + ih * Wo;
            #pragma unroll
            for (int kw = 0; kw < 3; ++kw) {
                int iw = ow + kw - 1;
                if (iw < 0 || iw >= Wo) continue;
                acc = fmaf(yr[iw], wc[kh * 3 + kw], acc);
            }
        }
    }
    y2[idx] = acc;
}

// ---------------- stats stage A: per (channel, n-slice) partial sum / sumsq ----------------
__global__ __launch_bounds__(256) void k_statsA(const float* __restrict__ y,
                                                float* __restrict__ part) {
    int c = blockIdx.x >> 4;
    int slice = blockIdx.x & 15;
    float s = 0.f, s2 = 0.f;
    constexpr int Q = HW / 4; // 196 float4 per (n,c) plane
    for (int j = threadIdx.x; j < 8 * Q; j += 256) {
        int n = slice * 8 + j / Q;
        int i = j % Q;
        float4 v = *((const float4*)(y + ((size_t)n * Cout + c) * HW) + i);
        s  += v.x + v.y + v.z + v.w;
        s2 += v.x * v.x + v.y * v.y + v.z * v.z + v.w * v.w;
    }
    block_reduce2(s, s2);
    if (threadIdx.x == 0) {
        part[(c * NSLICE + slice) * 2]     = s;
        part[(c * NSLICE + slice) * 2 + 1] = s2;
    }
}

// ---------------- stats stage B: finalize scale/shift per channel ----------------
__global__ void k_statsB(const float* __restrict__ part, const float* __restrict__ g,
                         const float* __restrict__ b, float* __restrict__ scale,
                         float* __restrict__ shift) {
    int c = threadIdx.x; // 128 threads
    float s = 0.f, s2 = 0.f;
    #pragma unroll
    for (int k = 0; k < NSLICE; ++k) {
        s  += part[(c * NSLICE + k) * 2];
        s2 += part[(c * NSLICE + k) * 2 + 1];
    }
    const float cnt = (float)B * (float)HW;
    float mean = s / cnt;
    float var  = s2 / cnt - mean * mean;
    float inv  = rsqrtf(var + EPS_);
    scale[c] = g[c] * inv;
    shift[c] = b[c] - mean * g[c] * inv;
}

// ---------------- in-place BN + ReLU on y1 ----------------
__global__ __launch_bounds__(256) void k_bnrelu(float* __restrict__ y,
        const float* __restrict__ scale, const float* __restrict__ shift) {
    int idx4 = blockIdx.x * 256 + threadIdx.x;
    int c = (idx4 / (HW / 4)) % Cout;
    float sc = scale[c], sh = shift[c];
    float4 v = ((const float4*)y)[idx4];
    v.x = fmaxf(fmaf(v.x, sc, sh), 0.f);
    v.y = fmaxf(fmaf(v.y, sc, sh), 0.f);
    v.z = fmaxf(fmaf(v.z, sc, sh), 0.f);
    v.w = fmaxf(fmaf(v.w, sc, sh), 0.f);
    ((float4*)y)[idx4] = v;
}

// ---------------- epilogue: out = relu(bn2(y2) + bnd(yd)); yd aliases out ----------------
__global__ __launch_bounds__(256) void k_final(
        const float* __restrict__ y2, const float* __restrict__ yd,
        const float* __restrict__ sc2, const float* __restrict__ sh2,
        const float* __restrict__ scd, const float* __restrict__ shd,
        float* __restrict__ out) {
    int idx4 = blockIdx.x * 256 + threadIdx.x;
    int c = (idx4 / (HW / 4)) % Cout;
    float s2c = sc2[c], h2c = sh2[c], sdc = scd[c], hdc = shd[c];
    float4 a = ((const float4*)y2)[idx4];
    float4 d = ((const float4*)yd)[idx4];
    float4 r;
    r.x = fmaxf(fmaf(a.x, s2c, h2c) + fmaf(d.x, sdc, hdc), 0.f);
    r.y = fmaxf(fmaf(a.y, s2c, h2c) + fmaf(d.y, sdc, hdc), 0.f);
    r.z = fmaxf(fmaf(a.z, s2c, h2c) + fmaf(d.z, sdc, hdc), 0.f);
    r.w = fmaxf(fmaf(a.w, s2c, h2c) + fmaf(d.w, sdc, hdc), 0.f);
    ((float4*)out)[idx4] = r;
}

extern "C" void kernel_launch(void* const* d_in, const int* in_sizes, int n_in,
                              void* d_out, int out_size, void* d_ws, size_t ws_size,
                              hipStream_t stream) {
    const float* x  = (const float*)d_in[0];
    const float* w1 = (const float*)d_in[1];
    const float* g1 = (const float*)d_in[2];
    const float* b1 = (const float*)d_in[3];
    const float* w2 = (const float*)d_in[4];
    const float* g2 = (const float*)d_in[5];
    const float* b2 = (const float*)d_in[6];
    const float* wd = (const float*)d_in[7];
    const float* gd = (const float*)d_in[8];
    const float* bd = (const float*)d_in[9];
    float* out = (float*)d_out;

    // workspace layout: y1, y2 big; partials + scale/shift small (~103 MB total)
    float* y1    = (float*)d_ws;
    float* y2    = y1 + NOUT;
    float* part1 = y2 + NOUT;
    float* partd = part1 + NPART;
    float* part2 = partd + NPART;
    float* sc1 = part2 + NPART; float* sh1 = sc1 + Cout;
    float* scd = sh1 + Cout;    float* shd = scd + Cout;
    float* sc2 = shd + Cout;    float* sh2 = sc2 + Cout;

    float* yd = out; // downsample branch lives in d_out until the epilogue

    k_conv1d<<<NOUT / 256, 256, 0, stream>>>(x, w1, wd, y1, yd);
    k_statsA<<<Cout * NSLICE, 256, 0, stream>>>(y1, part1);
    k_statsA<<<Cout * NSLICE, 256, 0, stream>>>(yd, partd);
    k_statsB<<<1, Cout, 0, stream>>>(part1, g1, b1, sc1, sh1);
    k_statsB<<<1, Cout, 0, stream>>>(partd, gd, bd, scd, shd);
    k_bnrelu<<<NOUT / 4 / 256, 256, 0, stream>>>(y1, sc1, sh1);
    k_conv2<<<NOUT / 256, 256, 0, stream>>>(y1, w2, y2);
    k_statsA<<<Cout * NSLICE, 256, 0, stream>>>(y2, part2);
    k_statsB<<<1, Cout, 0, stream>>>(part2, g2, b2, sc2, sh2);
    k_final<<<NOUT / 4 / 256, 256, 0, stream>>>(y2, yd, sc2, sh2, scd, shd, out);
}

// Round 2
// 278.122 us; speedup vs baseline: 29.0352x; 29.0352x over previous
//
#include <hip/hip_runtime.h>

// ---------------- problem dims ----------------
constexpr int B = 128, Cin = 64, H = 56, W = 56;
constexpr int Cout = 128, Ho = 28, Wo = 28;
constexpr int HW = Ho * Wo;                    // 784
constexpr int NPIX = B * HW;                   // 100352 output pixels
constexpr int NOUT = NPIX * Cout;              // 12,845,056
constexpr float EPS_ = 1e-5f;
constexpr float CNT_ = (float)NPIX;            // BN count per channel

// padded layouts
constexpr int HPX = 57, WPX = 57;              // x padded (hi edge only), NHWC C=64
constexpr int HP1 = 30, WP1 = 30;              // y1 padded (1 both sides), NHWC C=128

typedef __attribute__((ext_vector_type(8))) unsigned short u16x8;
typedef __attribute__((ext_vector_type(4))) unsigned short u16x4;
typedef __attribute__((ext_vector_type(8))) short bf16x8;
typedef __attribute__((ext_vector_type(4))) float f32x4;

__device__ inline float bf2f(unsigned short u) {
    union { unsigned int i; float f; } v; v.i = ((unsigned int)u) << 16; return v.f;
}
__device__ inline unsigned short f2bf(float f) {
    union { float f; unsigned int i; } v; v.f = f;
    return (unsigned short)((v.i + 0x7fffu + ((v.i >> 16) & 1u)) >> 16);
}

// async global->LDS, 16B per lane (wave-uniform LDS base + lane*16 implicit)
__device__ inline void gload16(const void* g, void* l) {
    __builtin_amdgcn_global_load_lds(
        (const __attribute__((address_space(1))) unsigned int*)g,
        (__attribute__((address_space(3))) unsigned int*)l, 16, 0, 0);
}

// ---------------- implicit-GEMM conv via MFMA ----------------
// A: pixels (M=100352) x K=(kh,kw,ci);  B: weights [co][K];  C: [pixel][co]
// xin: padded NHWC bf16; per-K-step source offset is wave-uniform.
template<int STRIDE, int HP, int WP, int CIN, int KHW, bool OUTPAD>
__global__ __launch_bounds__(256) void k_conv_mfma(
        const unsigned short* __restrict__ xin,
        const unsigned short* __restrict__ wt,
        unsigned short* __restrict__ yout) {
    constexpr int KTOT = KHW * KHW * CIN;
    constexpr int NSTEP = KTOT / 32;
    constexpr int CSTEPS = CIN / 32;
    __shared__ unsigned short Alds[128 * 32];
    __shared__ unsigned short Blds[128 * 32];
    const int tid = threadIdx.x, w = tid >> 6, l = tid & 63;
    const int wr = w >> 1, wc = w & 1;
    const int p0 = blockIdx.x * 128;
    const char* xb = (const char*)xin;
    const char* wb = (const char*)wt;

    int gA[2], gB[2], lofs[2];
    #pragma unroll
    for (int i = 0; i < 2; ++i) {
        int row = w * 32 + i * 16 + (l >> 2);
        int p = p0 + row;
        int n = p / HW, rr = p % HW;
        int oh = rr / Wo, ow = rr % Wo;
        gA[i] = (((n * HP + oh * STRIDE) * WP + ow * STRIDE) * CIN) * 2 + (l & 3) * 16;
        gB[i] = (row * KTOT) * 2 + (l & 3) * 16;   // row == co for B staging
        lofs[i] = row * 64 + (l & 3) * 16;
    }

    f32x4 acc[4][4];
    #pragma unroll
    for (int m = 0; m < 4; ++m)
        #pragma unroll
        for (int n = 0; n < 4; ++n)
            acc[m][n] = (f32x4){0.f, 0.f, 0.f, 0.f};

    for (int s = 0; s < NSTEP; ++s) {
        const int seg = s / CSTEPS;
        const int c0 = (s % CSTEPS) * 32;
        const int kh = seg / KHW, kw = seg % KHW;
        const int koffA = (((kh * WP + kw) * CIN) + c0) * 2;
        const int koffB = s * 64;
        gload16(xb + gA[0] + koffA, (char*)Alds + lofs[0]);
        gload16(xb + gA[1] + koffA, (char*)Alds + lofs[1]);
        gload16(wb + gB[0] + koffB, (char*)Blds + lofs[0]);
        gload16(wb + gB[1] + koffB, (char*)Blds + lofs[1]);
        __syncthreads();   // drains vmcnt: tiles resident
        bf16x8 af[4], bf[4];
        #pragma unroll
        for (int m = 0; m < 4; ++m)
            af[m] = *(const bf16x8*)((const char*)Alds + (wr * 64 + m * 16 + (l & 15)) * 64 + (l >> 4) * 16);
        #pragma unroll
        for (int n = 0; n < 4; ++n)
            bf[n] = *(const bf16x8*)((const char*)Blds + (wc * 64 + n * 16 + (l & 15)) * 64 + (l >> 4) * 16);
        #pragma unroll
        for (int m = 0; m < 4; ++m)
            #pragma unroll
            for (int n = 0; n < 4; ++n)
                acc[m][n] = __builtin_amdgcn_mfma_f32_16x16x32_bf16(af[m], bf[n], acc[m][n], 0, 0, 0);
        __syncthreads();   // frag reads done before next-step overwrite
    }

    // epilogue: C/D layout col(co)=l&15, row(pixel)=(l>>4)*4+reg
    if (OUTPAD) {
        // write into padded NHWC [n][30][30][128], interior offset +1 (borders stay 0)
        #pragma unroll
        for (int m = 0; m < 4; ++m) {
            #pragma unroll
            for (int r = 0; r < 4; ++r) {
                int p = p0 + wr * 64 + m * 16 + (l >> 4) * 4 + r;
                int n = p / HW, rr = p % HW;
                int oh = rr / Wo, ow = rr % Wo;
                unsigned short* dst = yout + ((size_t)((n * HP1 + oh + 1) * WP1 + ow + 1)) * 128
                                     + wc * 64 + (l & 15);
                #pragma unroll
                for (int q = 0; q < 4; ++q)
                    dst[q * 16] = f2bf(acc[m][q][r]);
            }
        }
    } else {
        // NCHW bf16: 4 regs = 4 consecutive pixels (784 is 4-aligned) -> u16x4 store
        #pragma unroll
        for (int m = 0; m < 4; ++m) {
            int pq = p0 + wr * 64 + m * 16 + (l >> 4) * 4;
            int n = pq / HW, rr = pq % HW;
            #pragma unroll
            for (int q = 0; q < 4; ++q) {
                int co = wc * 64 + q * 16 + (l & 15);
                u16x4 v;
                #pragma unroll
                for (int r = 0; r < 4; ++r) v[r] = f2bf(acc[m][q][r]);
                *(u16x4*)(yout + ((size_t)(n * Cout + co)) * HW + rr) = v;
            }
        }
    }
}

// ---------------- layout prep ----------------
// x NCHW f32 -> padded NHWC bf16 [n][57][57][64] (borders pre-zeroed by memset)
__global__ __launch_bounds__(256) void k_xprep(const float* __restrict__ x,
                                               unsigned short* __restrict__ xb) {
    int idx = blockIdx.x * 256 + threadIdx.x;      // over 128*56*56*8
    int cg = idx & 7, pix = idx >> 3;
    int n = pix / (H * W), rr = pix % (H * W);
    int ih = rr / W, iw = rr % W;
    const float* src = x + ((size_t)(n * Cin + cg * 8)) * (H * W) + ih * W + iw;
    u16x8 o;
    #pragma unroll
    for (int j = 0; j < 8; ++j) o[j] = f2bf(src[(size_t)j * (H * W)]);
    *(u16x8*)(xb + ((size_t)((n * HPX + ih) * WPX + iw)) * Cin + cg * 8) = o;
}

// w [co][ci][kh][kw] f32 -> wt [co][tap*cin+ci] bf16  (ntap=9 or 1)
__global__ void k_wprep(const float* __restrict__ w, unsigned short* __restrict__ wt,
                        int cin, int ntap) {
    int idx = blockIdx.x * 256 + threadIdx.x;
    if (idx >= 128 * cin * ntap) return;
    int co = idx / (cin * ntap), r = idx % (cin * ntap);
    int ci = r / ntap, tap = r % ntap;
    wt[co * cin * ntap + tap * cin + ci] = f2bf(w[idx]);
}

// ---------------- BN stats ----------------
__device__ inline void block_reduce2(float& s, float& s2) {
    #pragma unroll
    for (int off = 32; off > 0; off >>= 1) {
        s += __shfl_down(s, off);
        s2 += __shfl_down(s2, off);
    }
    __shared__ float ls[4], ls2[4];
    int wid = threadIdx.x >> 6, lane = threadIdx.x & 63;
    if (lane == 0) { ls[wid] = s; ls2[wid] = s2; }
    __syncthreads();
    if (threadIdx.x == 0) { s = ls[0] + ls[1] + ls[2] + ls[3]; s2 = ls2[0] + ls2[1] + ls2[2] + ls2[3]; }
}

// stats over bf16 NCHW (y2b / ydb): block = (c, n-slice)
__global__ __launch_bounds__(256) void k_stats_nchw(const unsigned short* __restrict__ y,
                                                    float* __restrict__ part) {
    int c = blockIdx.x >> 4, slice = blockIdx.x & 15;
    float s = 0.f, s2 = 0.f;
    for (int j = threadIdx.x; j < 8 * (HW / 8); j += 256) {
        int n = slice * 8 + j / (HW / 8), i = j % (HW / 8);
        u16x8 v = *(const u16x8*)(y + ((size_t)(n * Cout + c)) * HW + i * 8);
        #pragma unroll
        for (int e = 0; e < 8; ++e) { float f = bf2f(v[e]); s += f; s2 += f * f; }
    }
    block_reduce2(s, s2);
    if (threadIdx.x == 0) { part[(c * 16 + slice) * 2] = s; part[(c * 16 + slice) * 2 + 1] = s2; }
}

// stats over bf16 padded NHWC (y1p): zero borders contribute nothing
constexpr int NB_ST = 256;
__global__ __launch_bounds__(256) void k_stats_nhwc(const unsigned short* __restrict__ y,
                                                    float* __restrict__ part) {
    constexpr int NPIXP = B * HP1 * WP1;   // 115200
    int cg = threadIdx.x & 15, pr = threadIdx.x >> 4;
    float s[8], s2[8];
    #pragma unroll
    for (int e = 0; e < 8; ++e) { s[e] = 0.f; s2[e] = 0.f; }
    for (int p = blockIdx.x * 16 + pr; p < NPIXP; p += NB_ST * 16) {
        u16x8 v = *(const u16x8*)(y + (size_t)p * 128 + cg * 8);
        #pragma unroll
        for (int e = 0; e < 8; ++e) { float f = bf2f(v[e]); s[e] += f; s2[e] += f * f; }
    }
    __shared__ float red[256][16];
    #pragma unroll
    for (int e = 0; e < 8; ++e) { red[threadIdx.x][e] = s[e]; red[threadIdx.x][8 + e] = s2[e]; }
    __syncthreads();
    if (threadIdx.x < 128) {
        int c = threadIdx.x, g = c >> 3, e = c & 7;
        float ss = 0.f, qq = 0.f;
        for (int r = 0; r < 16; ++r) { ss += red[r * 16 + g][e]; qq += red[r * 16 + g][8 + e]; }
        part[((size_t)blockIdx.x * 128 + c) * 2] = ss;
        part[((size_t)blockIdx.x * 128 + c) * 2 + 1] = qq;
    }
}

// finalize scale/shift; part indexed (k*sk + c*sc)
__global__ void k_statsB(const float* __restrict__ part, int nk, int sk, int sc,
                         const float* __restrict__ g, const float* __restrict__ b,
                         float* __restrict__ scale, float* __restrict__ shift) {
    int c = threadIdx.x;
    float s = 0.f, s2 = 0.f;
    for (int k = 0; k < nk; ++k) {
        s += part[(k * sk + c * sc) * 2];
        s2 += part[(k * sk + c * sc) * 2 + 1];
    }
    float mean = s / CNT_;
    float var = s2 / CNT_ - mean * mean;
    float inv = rsqrtf(var + EPS_);
    scale[c] = g[c] * inv;
    shift[c] = b[c] - mean * g[c] * inv;
}

// BN+ReLU in-place on y1p interior (borders remain 0 from memset)
__global__ __launch_bounds__(256) void k_bnrelu(unsigned short* __restrict__ y,
        const float* __restrict__ sc, const float* __restrict__ sh) {
    int t = threadIdx.x, cg = t & 15, pl = t >> 4;
    int p = blockIdx.x * 16 + pl;                  // interior pixel 0..100351
    int n = p / HW, rr = p % HW;
    int oh = rr / Wo, ow = rr % Wo;
    size_t a = ((size_t)((n * HP1 + oh + 1) * WP1 + ow + 1)) * 128 + cg * 8;
    u16x8 v = *(u16x8*)(y + a);
    u16x8 o;
    #pragma unroll
    for (int e = 0; e < 8; ++e) {
        float f = bf2f(v[e]) * sc[cg * 8 + e] + sh[cg * 8 + e];
        o[e] = f2bf(fmaxf(f, 0.f));
    }
    *(u16x8*)(y + a) = o;
}

// out = relu(bn2(y2) + bnd(yd)), bf16 NCHW inputs -> f32 NCHW output
__global__ __launch_bounds__(256) void k_final(
        const unsigned short* __restrict__ y2, const unsigned short* __restrict__ yd,
        const float* __restrict__ sc2, const float* __restrict__ sh2,
        const float* __restrict__ scd, const float* __restrict__ shd,
        float* __restrict__ out) {
    int idx = blockIdx.x * 256 + threadIdx.x;      // 8-elem chunk id (784%8==0)
    int plane = idx / (HW / 8);                    // n*Cout + c
    int c = plane & (Cout - 1);
    int i = idx % (HW / 8);
    size_t a = (size_t)plane * HW + i * 8;
    u16x8 v2 = *(const u16x8*)(y2 + a);
    u16x8 vd = *(const u16x8*)(yd + a);
    float s2c = sc2[c], h2c = sh2[c], sdc = scd[c], hdc = shd[c];
    float4 r0, r1;
    r0.x = fmaxf(bf2f(v2[0]) * s2c + h2c + bf2f(vd[0]) * sdc + hdc, 0.f);
    r0.y = fmaxf(bf2f(v2[1]) * s2c + h2c + bf2f(vd[1]) * sdc + hdc, 0.f);
    r0.z = fmaxf(bf2f(v2[2]) * s2c + h2c + bf2f(vd[2]) * sdc + hdc, 0.f);
    r0.w = fmaxf(bf2f(v2[3]) * s2c + h2c + bf2f(vd[3]) * sdc + hdc, 0.f);
    r1.x = fmaxf(bf2f(v2[4]) * s2c + h2c + bf2f(vd[4]) * sdc + hdc, 0.f);
    r1.y = fmaxf(bf2f(v2[5]) * s2c + h2c + bf2f(vd[5]) * sdc + hdc, 0.f);
    r1.z = fmaxf(bf2f(v2[6]) * s2c + h2c + bf2f(vd[6]) * sdc + hdc, 0.f);
    r1.w = fmaxf(bf2f(v2[7]) * s2c + h2c + bf2f(vd[7]) * sdc + hdc, 0.f);
    *(float4*)(out + a) = r0;
    *(float4*)(out + a + 4) = r1;
}

extern "C" void kernel_launch(void* const* d_in, const int* in_sizes, int n_in,
                              void* d_out, int out_size, void* d_ws, size_t ws_size,
                              hipStream_t stream) {
    const float* x  = (const float*)d_in[0];
    const float* w1 = (const float*)d_in[1];
    const float* g1 = (const float*)d_in[2];
    const float* b1 = (const float*)d_in[3];
    const float* w2 = (const float*)d_in[4];
    const float* g2 = (const float*)d_in[5];
    const float* b2 = (const float*)d_in[6];
    const float* wd = (const float*)d_in[7];
    const float* gd = (const float*)d_in[8];
    const float* bd = (const float*)d_in[9];
    float* out = (float*)d_out;

    char* ws = (char*)d_ws;
    auto alloc = [&](size_t bytes) { char* p = ws; ws += (bytes + 255) & ~(size_t)255; return p; };
    const size_t XB_BYTES  = (size_t)B * HPX * WPX * Cin * 2;   // 53.2 MB
    const size_t Y1P_BYTES = (size_t)B * HP1 * WP1 * Cout * 2;  // 29.5 MB
    unsigned short* xb  = (unsigned short*)alloc(XB_BYTES);
    unsigned short* y1p = (unsigned short*)alloc(Y1P_BYTES);
    unsigned short* y2b = (unsigned short*)alloc((size_t)NOUT * 2);
    unsigned short* ydb = (unsigned short*)alloc((size_t)NOUT * 2);
    unsigned short* wt1 = (unsigned short*)alloc((size_t)Cout * 576 * 2);
    unsigned short* wt2 = (unsigned short*)alloc((size_t)Cout * 1152 * 2);
    unsigned short* wtd = (unsigned short*)alloc((size_t)Cout * 64 * 2);
    float* partN = (float*)alloc((size_t)NB_ST * 128 * 2 * 4);
    float* part2 = (float*)alloc(128 * 16 * 2 * 4);
    float* partd = (float*)alloc(128 * 16 * 2 * 4);
    float* sc1 = (float*)alloc(128 * 4); float* sh1 = (float*)alloc(128 * 4);
    float* sc2 = (float*)alloc(128 * 4); float* sh2 = (float*)alloc(128 * 4);
    float* scd = (float*)alloc(128 * 4); float* shd = (float*)alloc(128 * 4);

    // zero padded buffers (borders must be 0; stats sum zeros harmlessly)
    hipMemsetAsync(xb, 0, XB_BYTES, stream);
    hipMemsetAsync(y1p, 0, Y1P_BYTES, stream);

    k_xprep<<<(B * H * W * 8) / 256, 256, 0, stream>>>(x, xb);
    k_wprep<<<(128 * 64 * 9 + 255) / 256, 256, 0, stream>>>(w1, wt1, 64, 9);
    k_wprep<<<(128 * 128 * 9 + 255) / 256, 256, 0, stream>>>(w2, wt2, 128, 9);
    k_wprep<<<(128 * 64 + 255) / 256, 256, 0, stream>>>(wd, wtd, 64, 1);

    // conv1: 3x3 s2 -> padded NHWC bf16
    k_conv_mfma<2, HPX, WPX, 64, 3, true><<<NPIX / 128, 256, 0, stream>>>(xb, wt1, y1p);
    // downsample: 1x1 s2 -> NCHW bf16
    k_conv_mfma<2, HPX, WPX, 64, 1, false><<<NPIX / 128, 256, 0, stream>>>(xb, wtd, ydb);

    k_stats_nhwc<<<NB_ST, 256, 0, stream>>>(y1p, partN);
    k_statsB<<<1, 128, 0, stream>>>(partN, NB_ST, 128, 1, g1, b1, sc1, sh1);
    k_bnrelu<<<NPIX / 16, 256, 0, stream>>>(y1p, sc1, sh1);

    // conv2: 3x3 s1 -> NCHW bf16
    k_conv_mfma<1, HP1, WP1, 128, 3, false><<<NPIX / 128, 256, 0, stream>>>(y1p, wt2, y2b);

    k_stats_nchw<<<Cout * 16, 256, 0, stream>>>(y2b, part2);
    k_statsB<<<1, 128, 0, stream>>>(part2, 16, 1, 16, g2, b2, sc2, sh2);
    k_stats_nchw<<<Cout * 16, 256, 0, stream>>>(ydb, partd);
    k_statsB<<<1, 128, 0, stream>>>(partd, 16, 1, 16, gd, bd, scd, shd);

    k_final<<<NOUT / 8 / 256, 256, 0, stream>>>(y2b, ydb, sc2, sh2, scd, shd, out);
}

// Round 3
// 193.134 us; speedup vs baseline: 41.8121x; 1.4400x over previous
//
#include <hip/hip_runtime.h>

// ---------------- problem dims ----------------
constexpr int B = 128, Cin = 64, H = 56, W = 56;
constexpr int Cout = 128, Ho = 28, Wo = 28;
constexpr int HW = Ho * Wo;                    // 784
constexpr int NPIX = B * HW;                   // 100352 output pixels
constexpr int NOUT = NPIX * Cout;              // 12,845,056
constexpr int NBLK = NPIX / 128;               // 784 conv blocks
constexpr float EPS_ = 1e-5f;
constexpr float CNT_ = (float)NPIX;

// padded layouts
constexpr int HPX = 57, WPX = 57;              // x padded (hi edge only), NHWC C=64
constexpr int HP1 = 30, WP1 = 30;              // y1 padded (1 both sides), NHWC C=128

typedef __attribute__((ext_vector_type(8))) unsigned short u16x8;
typedef __attribute__((ext_vector_type(4))) unsigned short u16x4;
typedef __attribute__((ext_vector_type(8))) short bf16x8;
typedef __attribute__((ext_vector_type(4))) float f32x4;

__device__ inline float bf2f(unsigned short u) {
    union { unsigned int i; float f; } v; v.i = ((unsigned int)u) << 16; return v.f;
}
__device__ inline unsigned short f2bf(float f) {
    union { float f; unsigned int i; } v; v.f = f;
    return (unsigned short)((v.i + 0x7fffu + ((v.i >> 16) & 1u)) >> 16);
}

__device__ inline void gload16(const void* g, void* l) {
    __builtin_amdgcn_global_load_lds(
        (const __attribute__((address_space(1))) unsigned int*)g,
        (__attribute__((address_space(3))) unsigned int*)l, 16, 0, 0);
}

// ---------------- implicit-GEMM conv via MFMA (+ fused BN partial sums) ----------------
template<int STRIDE, int HP, int WP, int CIN, int KHW, bool OUTPAD>
__global__ __launch_bounds__(256) void k_conv_mfma(
        const unsigned short* __restrict__ xin,
        const unsigned short* __restrict__ wt,
        unsigned short* __restrict__ yout,
        float* __restrict__ part) {
    constexpr int KTOT = KHW * KHW * CIN;
    constexpr int NSTEP = KTOT / 32;
    constexpr int CSTEPS = CIN / 32;
    __shared__ unsigned short Alds[128 * 32];
    __shared__ unsigned short Blds[128 * 32];
    const int tid = threadIdx.x, w = tid >> 6, l = tid & 63;
    const int wr = w >> 1, wc = w & 1;
    const int p0 = blockIdx.x * 128;
    const char* xb = (const char*)xin;
    const char* wb = (const char*)wt;

    int gA[2], gB[2], lofs[2];
    #pragma unroll
    for (int i = 0; i < 2; ++i) {
        int row = w * 32 + i * 16 + (l >> 2);
        int p = p0 + row;
        int n = p / HW, rr = p % HW;
        int oh = rr / Wo, ow = rr % Wo;
        gA[i] = (((n * HP + oh * STRIDE) * WP + ow * STRIDE) * CIN) * 2 + (l & 3) * 16;
        gB[i] = (row * KTOT) * 2 + (l & 3) * 16;
        lofs[i] = row * 64 + (l & 3) * 16;
    }

    f32x4 acc[4][4];
    #pragma unroll
    for (int m = 0; m < 4; ++m)
        #pragma unroll
        for (int n = 0; n < 4; ++n)
            acc[m][n] = (f32x4){0.f, 0.f, 0.f, 0.f};

    for (int s = 0; s < NSTEP; ++s) {
        const int seg = s / CSTEPS;
        const int c0 = (s % CSTEPS) * 32;
        const int kh = seg / KHW, kw = seg % KHW;
        const int koffA = (((kh * WP + kw) * CIN) + c0) * 2;
        const int koffB = s * 64;
        gload16(xb + gA[0] + koffA, (char*)Alds + lofs[0]);
        gload16(xb + gA[1] + koffA, (char*)Alds + lofs[1]);
        gload16(wb + gB[0] + koffB, (char*)Blds + lofs[0]);
        gload16(wb + gB[1] + koffB, (char*)Blds + lofs[1]);
        __syncthreads();
        bf16x8 af[4], bf[4];
        #pragma unroll
        for (int m = 0; m < 4; ++m)
            af[m] = *(const bf16x8*)((const char*)Alds + (wr * 64 + m * 16 + (l & 15)) * 64 + (l >> 4) * 16);
        #pragma unroll
        for (int n = 0; n < 4; ++n)
            bf[n] = *(const bf16x8*)((const char*)Blds + (wc * 64 + n * 16 + (l & 15)) * 64 + (l >> 4) * 16);
        #pragma unroll
        for (int m = 0; m < 4; ++m)
            #pragma unroll
            for (int n = 0; n < 4; ++n)
                acc[m][n] = __builtin_amdgcn_mfma_f32_16x16x32_bf16(af[m], bf[n], acc[m][n], 0, 0, 0);
        __syncthreads();
    }

    // ---- store: C/D layout col(co)=l&15, row(pixel)=(l>>4)*4+reg ----
    if (OUTPAD) {
        #pragma unroll
        for (int m = 0; m < 4; ++m) {
            #pragma unroll
            for (int r = 0; r < 4; ++r) {
                int p = p0 + wr * 64 + m * 16 + (l >> 4) * 4 + r;
                int n = p / HW, rr = p % HW;
                int oh = rr / Wo, ow = rr % Wo;
                unsigned short* dst = yout + ((size_t)((n * HP1 + oh + 1) * WP1 + ow + 1)) * 128
                                     + wc * 64 + (l & 15);
                #pragma unroll
                for (int q = 0; q < 4; ++q)
                    dst[q * 16] = f2bf(acc[m][q][r]);
            }
        }
    } else {
        #pragma unroll
        for (int m = 0; m < 4; ++m) {
            int pq = p0 + wr * 64 + m * 16 + (l >> 4) * 4;
            int n = pq / HW, rr = pq % HW;
            #pragma unroll
            for (int q = 0; q < 4; ++q) {
                int co = wc * 64 + q * 16 + (l & 15);
                u16x4 v;
                #pragma unroll
                for (int r = 0; r < 4; ++r) v[r] = f2bf(acc[m][q][r]);
                *(u16x4*)(yout + ((size_t)(n * Cout + co)) * HW + rr) = v;
            }
        }
    }

    // ---- fused per-channel BN partials from acc (f32, pre-rounding) ----
    __shared__ float lsum[4][64], lsq[4][64];
    float ps[4], pq_[4];
    #pragma unroll
    for (int n = 0; n < 4; ++n) {
        float s = 0.f, q = 0.f;
        #pragma unroll
        for (int m = 0; m < 4; ++m)
            #pragma unroll
            for (int r = 0; r < 4; ++r) { float v = acc[m][n][r]; s += v; q += v * v; }
        s += __shfl_xor(s, 16); q += __shfl_xor(q, 16);
        s += __shfl_xor(s, 32); q += __shfl_xor(q, 32);
        ps[n] = s; pq_[n] = q;
    }
    if (l < 16) {
        #pragma unroll
        for (int n = 0; n < 4; ++n) { lsum[w][n * 16 + l] = ps[n]; lsq[w][n * 16 + l] = pq_[n]; }
    }
    __syncthreads();
    if (tid < 128) {
        int c = tid, half = c >> 6, j = c & 63;
        float s = lsum[half][j] + lsum[half + 2][j];
        float q = lsq[half][j] + lsq[half + 2][j];
        part[((size_t)blockIdx.x * 128 + c) * 2]     = s;
        part[((size_t)blockIdx.x * 128 + c) * 2 + 1] = q;
    }
}

// ---------------- border zeroing (replaces 83MB memsets) ----------------
__global__ __launch_bounds__(256) void k_zerob(unsigned short* __restrict__ xb,
                                               unsigned short* __restrict__ y1p) {
    int idx = blockIdx.x * 256 + threadIdx.x;
    constexpr int NA = B * 113 * 8;      // xb border: (ih=56 row: 57) + (iw=56 col: 56)
    const u16x8 z = (u16x8){0, 0, 0, 0, 0, 0, 0, 0};
    if (idx < NA) {
        int cg = idx & 7; int t = idx >> 3;
        int bp = t % 113, n = t / 113;
        int ih = bp < 57 ? 56 : bp - 57;
        int iw = bp < 57 ? bp : 56;
        *(u16x8*)(xb + ((size_t)((n * HPX + ih) * WPX + iw)) * Cin + cg * 8) = z;
    } else {
        idx -= NA;
        if (idx >= B * 116 * 16) return;  // y1p ring: 2*30 + 2*28 = 116 pixels
        int cg = idx & 15; int t = idx >> 4;
        int bp = t % 116, n = t / 116;
        int oh, ow;
        if (bp < 30)      { oh = 0;           ow = bp; }
        else if (bp < 60) { oh = 29;          ow = bp - 30; }
        else if (bp < 88) { oh = bp - 60 + 1; ow = 0; }
        else              { oh = bp - 88 + 1; ow = 29; }
        *(u16x8*)(y1p + ((size_t)((n * HP1 + oh) * WP1 + ow)) * 128 + cg * 8) = z;
    }
}

// ---------------- layout prep ----------------
// x NCHW f32 -> padded NHWC bf16, one block per (n, ih) row, LDS transpose
__global__ __launch_bounds__(256) void k_xprep(const float* __restrict__ x,
                                               unsigned short* __restrict__ xb) {
    __shared__ unsigned short lds[64 * 57];
    int n = blockIdx.x / H, ih = blockIdx.x % H;
    const float* src = x + ((size_t)n * Cin * H + ih) * W;   // + c*H*W + iw
    for (int j = threadIdx.x; j < Cin * W; j += 256) {
        int c = j / W, iw = j % W;
        lds[c * 57 + iw] = f2bf(src[(size_t)c * H * W + iw]);
    }
    __syncthreads();
    unsigned short* dst = xb + ((size_t)(n * HPX + ih)) * WPX * Cin;
    for (int k = threadIdx.x; k < W * 8; k += 256) {
        int pix = k >> 3, cg = k & 7;
        u16x8 v;
        #pragma unroll
        for (int e = 0; e < 8; ++e) v[e] = lds[(cg * 8 + e) * 57 + pix];
        *(u16x8*)(dst + pix * Cin + cg * 8) = v;
    }
}

// all three weight preps in one launch; w [co][ci][kh][kw] -> wt [co][tap*cin+ci]
__global__ void k_wprep_all(const float* __restrict__ w1, const float* __restrict__ w2,
                            const float* __restrict__ wd,
                            unsigned short* __restrict__ wt1, unsigned short* __restrict__ wt2,
                            unsigned short* __restrict__ wtd) {
    int idx = blockIdx.x * 256 + threadIdx.x;
    const float* w; unsigned short* wt; int cin, ntap;
    if (idx < 73728)            { w = w1; wt = wt1; cin = 64;  ntap = 9; }
    else if (idx < 73728 + 147456) { idx -= 73728; w = w2; wt = wt2; cin = 128; ntap = 9; }
    else if (idx < 73728 + 147456 + 8192) { idx -= 73728 + 147456; w = wd; wt = wtd; cin = 64; ntap = 1; }
    else return;
    int co = idx / (cin * ntap), r = idx % (cin * ntap);
    int ci = r / ntap, tap = r % ntap;
    wt[co * cin * ntap + tap * cin + ci] = f2bf(w[idx]);
}

// ---------------- BN finalize ----------------
__device__ inline void block_reduce2(float& s, float& s2) {
    #pragma unroll
    for (int off = 32; off > 0; off >>= 1) {
        s += __shfl_down(s, off);
        s2 += __shfl_down(s2, off);
    }
    __shared__ float ls[4], ls2[4];
    int wid = threadIdx.x >> 6, lane = threadIdx.x & 63;
    if (lane == 0) { ls[wid] = s; ls2[wid] = s2; }
    __syncthreads();
    if (threadIdx.x == 0) { s = ls[0] + ls[1] + ls[2] + ls[3]; s2 = ls2[0] + ls2[1] + ls2[2] + ls2[3]; }
}

// one block per channel (grid 128 or 256); blocks >=128 take the B-set
__global__ __launch_bounds__(256) void k_finalize(
        const float* __restrict__ pA, const float* __restrict__ pB,
        const float* __restrict__ gA, const float* __restrict__ bA,
        const float* __restrict__ gB, const float* __restrict__ bB,
        float* __restrict__ scA, float* __restrict__ shA,
        float* __restrict__ scB, float* __restrict__ shB) {
    const bool second = blockIdx.x >= 128;
    const int c = blockIdx.x & 127;
    const float* part = second ? pB : pA;
    const float* g = second ? gB : gA;
    const float* b = second ? bB : bA;
    float* scale = second ? scB : scA;
    float* shift = second ? shB : shA;
    float s = 0.f, q = 0.f;
    for (int k = threadIdx.x; k < NBLK; k += 256) {
        s += part[((size_t)k * 128 + c) * 2];
        q += part[((size_t)k * 128 + c) * 2 + 1];
    }
    block_reduce2(s, q);
    if (threadIdx.x == 0) {
        float mean = s / CNT_;
        float var = q / CNT_ - mean * mean;
        float inv = rsqrtf(var + EPS_);
        scale[c] = g[c] * inv;
        shift[c] = b[c] - mean * g[c] * inv;
    }
}

// BN+ReLU in-place on y1p interior
__global__ __launch_bounds__(256) void k_bnrelu(unsigned short* __restrict__ y,
        const float* __restrict__ sc, const float* __restrict__ sh) {
    int t = threadIdx.x, cg = t & 15, pl = t >> 4;
    int p = blockIdx.x * 16 + pl;
    int n = p / HW, rr = p % HW;
    int oh = rr / Wo, ow = rr % Wo;
    size_t a = ((size_t)((n * HP1 + oh + 1) * WP1 + ow + 1)) * 128 + cg * 8;
    u16x8 v = *(u16x8*)(y + a);
    u16x8 o;
    #pragma unroll
    for (int e = 0; e < 8; ++e) {
        float f = bf2f(v[e]) * sc[cg * 8 + e] + sh[cg * 8 + e];
        o[e] = f2bf(fmaxf(f, 0.f));
    }
    *(u16x8*)(y + a) = o;
}

// out = relu(bn2(y2) + bnd(yd)), bf16 NCHW -> f32 NCHW
__global__ __launch_bounds__(256) void k_final(
        const unsigned short* __restrict__ y2, const unsigned short* __restrict__ yd,
        const float* __restrict__ sc2, const float* __restrict__ sh2,
        const float* __restrict__ scd, const float* __restrict__ shd,
        float* __restrict__ out) {
    int idx = blockIdx.x * 256 + threadIdx.x;
    int plane = idx / (HW / 8);
    int c = plane & (Cout - 1);
    int i = idx % (HW / 8);
    size_t a = (size_t)plane * HW + i * 8;
    u16x8 v2 = *(const u16x8*)(y2 + a);
    u16x8 vd = *(const u16x8*)(yd + a);
    float s2c = sc2[c], h2c = sh2[c], sdc = scd[c], hdc = shd[c];
    float4 r0, r1;
    r0.x = fmaxf(bf2f(v2[0]) * s2c + h2c + bf2f(vd[0]) * sdc + hdc, 0.f);
    r0.y = fmaxf(bf2f(v2[1]) * s2c + h2c + bf2f(vd[1]) * sdc + hdc, 0.f);
    r0.z = fmaxf(bf2f(v2[2]) * s2c + h2c + bf2f(vd[2]) * sdc + hdc, 0.f);
    r0.w = fmaxf(bf2f(v2[3]) * s2c + h2c + bf2f(vd[3]) * sdc + hdc, 0.f);
    r1.x = fmaxf(bf2f(v2[4]) * s2c + h2c + bf2f(vd[4]) * sdc + hdc, 0.f);
    r1.y = fmaxf(bf2f(v2[5]) * s2c + h2c + bf2f(vd[5]) * sdc + hdc, 0.f);
    r1.z = fmaxf(bf2f(v2[6]) * s2c + h2c + bf2f(vd[6]) * sdc + hdc, 0.f);
    r1.w = fmaxf(bf2f(v2[7]) * s2c + h2c + bf2f(vd[7]) * sdc + hdc, 0.f);
    *(float4*)(out + a) = r0;
    *(float4*)(out + a + 4) = r1;
}

extern "C" void kernel_launch(void* const* d_in, const int* in_sizes, int n_in,
                              void* d_out, int out_size, void* d_ws, size_t ws_size,
                              hipStream_t stream) {
    const float* x  = (const float*)d_in[0];
    const float* w1 = (const float*)d_in[1];
    const float* g1 = (const float*)d_in[2];
    const float* b1 = (const float*)d_in[3];
    const float* w2 = (const float*)d_in[4];
    const float* g2 = (const float*)d_in[5];
    const float* b2 = (const float*)d_in[6];
    const float* wd = (const float*)d_in[7];
    const float* gd = (const float*)d_in[8];
    const float* bd = (const float*)d_in[9];
    float* out = (float*)d_out;

    char* ws = (char*)d_ws;
    auto alloc = [&](size_t bytes) { char* p = ws; ws += (bytes + 255) & ~(size_t)255; return p; };
    unsigned short* xb  = (unsigned short*)alloc((size_t)B * HPX * WPX * Cin * 2);
    unsigned short* y1p = (unsigned short*)alloc((size_t)B * HP1 * WP1 * Cout * 2);
    unsigned short* y2b = (unsigned short*)alloc((size_t)NOUT * 2);
    unsigned short* ydb = (unsigned short*)alloc((size_t)NOUT * 2);
    unsigned short* wt1 = (unsigned short*)alloc((size_t)Cout * 576 * 2);
    unsigned short* wt2 = (unsigned short*)alloc((size_t)Cout * 1152 * 2);
    unsigned short* wtd = (unsigned short*)alloc((size_t)Cout * 64 * 2);
    float* part1 = (float*)alloc((size_t)NBLK * 128 * 2 * 4);
    float* part2 = (float*)alloc((size_t)NBLK * 128 * 2 * 4);
    float* partd = (float*)alloc((size_t)NBLK * 128 * 2 * 4);
    float* sc1 = (float*)alloc(128 * 4); float* sh1 = (float*)alloc(128 * 4);
    float* sc2 = (float*)alloc(128 * 4); float* sh2 = (float*)alloc(128 * 4);
    float* scd = (float*)alloc(128 * 4); float* shd = (float*)alloc(128 * 4);

    k_zerob<<<(B * 113 * 8 + B * 116 * 16 + 255) / 256, 256, 0, stream>>>(xb, y1p);
    k_xprep<<<B * H, 256, 0, stream>>>(x, xb);
    k_wprep_all<<<(73728 + 147456 + 8192 + 255) / 256, 256, 0, stream>>>(w1, w2, wd, wt1, wt2, wtd);

    // conv1: 3x3 s2 -> padded NHWC bf16 (+part1)
    k_conv_mfma<2, HPX, WPX, 64, 3, true><<<NBLK, 256, 0, stream>>>(xb, wt1, y1p, part1);
    // downsample: 1x1 s2 -> NCHW bf16 (+partd)
    k_conv_mfma<2, HPX, WPX, 64, 1, false><<<NBLK, 256, 0, stream>>>(xb, wtd, ydb, partd);

    k_finalize<<<128, 256, 0, stream>>>(part1, part1, g1, b1, g1, b1, sc1, sh1, sc1, sh1);
    k_bnrelu<<<NPIX / 16, 256, 0, stream>>>(y1p, sc1, sh1);

    // conv2: 3x3 s1 -> NCHW bf16 (+part2)
    k_conv_mfma<1, HP1, WP1, 128, 3, false><<<NBLK, 256, 0, stream>>>(y1p, wt2, y2b, part2);

    k_finalize<<<256, 256, 0, stream>>>(part2, partd, g2, b2, gd, bd, sc2, sh2, scd, shd);

    k_final<<<NOUT / 8 / 256, 256, 0, stream>>>(y2b, ydb, sc2, sh2, scd, shd, out);
}